// Round 11
// baseline (133.001 us; speedup 1.0000x reference)
//
#include <hip/hip_runtime.h>

#define TAU 0.25f
#define SIGMA 0.5f

typedef _Float16 fp16;
typedef fp16 half8 __attribute__((ext_vector_type(8)));

constexpr int H = 1024, W = 1024, C = 3;
constexpr int WC  = W * C;         // 3072 elems per row
constexpr int VEC = 8;
constexpr int CPR = WC / VEC;      // 384 chunks per row
constexpr int TPB = 768;           // threads per block
constexpr int RB  = 4;             // rows per block
constexpr int NB  = H / RB;        // 256 blocks = 1 per CU
constexpr int ITS = 20;
constexpr int FSTRIDE = 32;        // flag padding: 128 B per block

__device__ __forceinline__ float clampw(float v, float w) {
    return fminf(fmaxf(v, -w), w);
}

__device__ __forceinline__ void ld8(const float* __restrict__ p, int i, float* v) {
    float4 a = *(const float4*)(p + i);
    float4 b = *(const float4*)(p + i + 4);
    v[0]=a.x; v[1]=a.y; v[2]=a.z; v[3]=a.w;
    v[4]=b.x; v[5]=b.y; v[6]=b.z; v[7]=b.w;
}

// agent-scope relaxed 16B store/load (coherent at L3; R8-proven)
__device__ __forceinline__ void pub_store(fp16* dst, half8 v) {
    union { half8 h; unsigned long long q[2]; } cv; cv.h = v;
    __hip_atomic_store((unsigned long long*)dst,     cv.q[0],
                       __ATOMIC_RELAXED, __HIP_MEMORY_SCOPE_AGENT);
    __hip_atomic_store((unsigned long long*)dst + 1, cv.q[1],
                       __ATOMIC_RELAXED, __HIP_MEMORY_SCOPE_AGENT);
}
__device__ __forceinline__ half8 pub_load(const fp16* src) {
    union { unsigned long long q[2]; half8 h; } cv;
    cv.q[0] = __hip_atomic_load((const unsigned long long*)src,
                                __ATOMIC_RELAXED, __HIP_MEMORY_SCOPE_AGENT);
    cv.q[1] = __hip_atomic_load((const unsigned long long*)src + 1,
                                __ATOMIC_RELAXED, __HIP_MEMORY_SCOPE_AGENT);
    return cv.h;
}

// Persistent kernel: 20 CP iterations, state in LDS; u/tb/rc in f32 registers.
// Sync skeleton is R8's proven pattern: B2 -> flag -> 2-thread spin ->
// barrier -> import -> B3.  (R9/R10's early-flag + fused spin diverged
// under graph replay; reverted.)
__global__ __launch_bounds__(TPB, 3) void tv_persist(
    const float* __restrict__ dx, const float* __restrict__ dy,
    const float* __restrict__ dc, const float* __restrict__ db,
    const float* __restrict__ di, float* __restrict__ out,
    fp16* __restrict__ pub0, fp16* __restrict__ pub1,
    int* __restrict__ prog)
{
    __shared__ fp16 s_ub[6][WC];   // rows y0-1 .. y0+4 (idx = r - y0 + 1)
    __shared__ fp16 s_px[4][WC];   // rows y0   .. y0+3
    __shared__ fp16 s_py[5][WC];   // idx0 = shadow row y0-1; idx r+1 = row y0+r
    // 92,160 B total

    const int b   = blockIdx.x;
    const int y0  = b * RB;
    const int tid = threadIdx.x;
    const bool hasTop = (b > 0), hasBot = (b < NB - 1);

    const int cx  = tid % CPR;
    const int rA  = tid / CPR;         // 0 or 1; thread owns rows rA and rA+2
    const int xc0 = cx * VEC;

    // ---- init: LDS state + register invariants (tb,rc,u in f32) ----
    half8 wxr[2], wyr[2];
    float tbf[2][8], rcf[2][8], uf[2][8];
    #pragma unroll
    for (int k = 0; k < 2; ++k) {
        int r  = rA + 2 * k;
        int gi = (y0 + r) * WC + xc0;
        float vv[8], cv[8], bv[8], xv[8], yv[8];
        ld8(di, gi, vv); ld8(dc, gi, cv); ld8(db, gi, bv);
        ld8(dx, gi, xv); ld8(dy, gi, yv);
        half8 hub, hz;
        #pragma unroll
        for (int j = 0; j < 8; ++j) {
            hub[j] = (fp16)vv[j];
            wxr[k][j] = (fp16)xv[j];
            wyr[k][j] = (fp16)yv[j];
            tbf[k][j] = TAU * cv[j] * bv[j];
            rcf[k][j] = 1.0f / (1.0f + TAU * cv[j]);
            uf[k][j]  = vv[j];
            hz[j] = (fp16)0.f;
        }
        *(half8*)&s_ub[r + 1][xc0] = hub;
        *(half8*)&s_px[r][xc0]     = hz;
        *(half8*)&s_py[r + 1][xc0] = hz;
    }
    half8 wyS = {};
    if (tid < CPR) {
        if (hasTop) {                       // halo row y0-1: ub, shadow py, wy
            int x0 = tid * VEC;
            int gi = (y0 - 1) * WC + x0;
            float vv[8], yv[8];
            ld8(di, gi, vv); ld8(dy, gi, yv);
            half8 h, hz;
            #pragma unroll
            for (int j = 0; j < 8; ++j) { h[j] = (fp16)vv[j]; wyS[j] = (fp16)yv[j]; hz[j] = (fp16)0.f; }
            *(half8*)&s_ub[0][x0] = h;
            *(half8*)&s_py[0][x0] = hz;
        }
    } else {
        if (hasBot) {                       // halo row y0+4: ub
            int x0 = (tid - CPR) * VEC;
            int gi = (y0 + 4) * WC + x0;
            float vv[8];
            ld8(di, gi, vv);
            half8 h;
            #pragma unroll
            for (int j = 0; j < 8; ++j) h[j] = (fp16)vv[j];
            *(half8*)&s_ub[5][x0] = h;
        }
    }
    __syncthreads();

    half8 pxn[2], pyn[2];
    for (int t = 0; t < ITS; ++t) {
        // ---------------- dual phase ----------------
        #pragma unroll
        for (int k = 0; k < 2; ++k) {
            int r = rA + 2 * k;
            bool notBot = (y0 + r < H - 1);
            half8 ubC = *(half8*)&s_ub[r + 1][xc0];
            half8 ubN = (cx < CPR - 1) ? *(half8*)&s_ub[r + 1][xc0 + 8] : ubC;
            half8 ubD = *(half8*)&s_ub[r + 2][xc0];   // idx5 = halo (unused if !notBot)
            half8 pxo = *(half8*)&s_px[r][xc0];
            half8 pyo = *(half8*)&s_py[r + 1][xc0];
            half8 npx, npy;
            #pragma unroll
            for (int j = 0; j < 8; ++j) {
                float ub  = (float)ubC[j];
                float ubR = (j < 5) ? (float)ubC[j + 3] : (float)ubN[j - 5];
                float gx  = (xc0 + j < WC - C) ? (ubR - ub) : 0.0f;
                float gy  = notBot ? ((float)ubD[j] - ub) : 0.0f;
                npx[j] = (fp16)clampw((float)pxo[j] + SIGMA * gx, (float)wxr[k][j]);
                npy[j] = (fp16)clampw((float)pyo[j] + SIGMA * gy, (float)wyr[k][j]);
            }
            *(half8*)&s_px[r][xc0]     = npx;   // only this thread read the old value
            *(half8*)&s_py[r + 1][xc0] = npy;
            pxn[k] = npx; pyn[k] = npy;
        }
        if (hasTop && tid < CPR) {              // shadow py row y0-1
            int x0 = tid * VEC;
            half8 u0 = *(half8*)&s_ub[0][x0];
            half8 u1 = *(half8*)&s_ub[1][x0];
            half8 po = *(half8*)&s_py[0][x0];
            half8 np;
            #pragma unroll
            for (int j = 0; j < 8; ++j)
                np[j] = (fp16)clampw((float)po[j] + SIGMA * ((float)u1[j] - (float)u0[j]),
                                     (float)wyS[j]);
            *(half8*)&s_py[0][x0] = np;
        }
        __syncthreads();                        // B1: px,py visible

        // ---------------- primal phase (both rows) ----------------
        #pragma unroll
        for (int k = 0; k < 2; ++k) {
            int r = rA + 2 * k;
            bool notTop = (y0 + r > 0);
            half8 px8 = pxn[k], py8 = pyn[k];
            half8 pxP = (cx > 0) ? *(half8*)&s_px[r][xc0 - 8] : px8;
            half8 pyU = *(half8*)&s_py[r][xc0];   // r==0 -> shadow row
            half8 nub;
            float un8[8];
            #pragma unroll
            for (int j = 0; j < 8; ++j) {
                float d = (float)px8[j] + (float)py8[j];
                float pxL = (j >= 3) ? (float)px8[j - 3] : (float)pxP[j + 5];
                d -= (xc0 + j >= C) ? pxL : 0.0f;
                d -= notTop ? (float)pyU[j] : 0.0f;
                float uo = uf[k][j];
                float un = (uo + TAU * d + tbf[k][j]) * rcf[k][j];
                un8[j] = un;
                uf[k][j] = un;
                nub[j] = (fp16)(2.0f * un - uo);
            }
            *(half8*)&s_ub[r + 1][xc0] = nub;
            if (t == ITS - 1) {
                int gi = (y0 + r) * WC + xc0;
                *(float4*)(out + gi)     = make_float4(un8[0], un8[1], un8[2], un8[3]);
                *(float4*)(out + gi + 4) = make_float4(un8[4], un8[5], un8[6], un8[7]);
            } else {
                fp16* pub = (t & 1) ? pub1 : pub0;
                if (r == 0) pub_store(&pub[(b * 2 + 0) * WC + xc0], nub);  // top row
                if (r == 3) pub_store(&pub[(b * 2 + 1) * WC + xc0], nub);  // bottom row
            }
        }

        if (t < ITS - 1) {
            // all waves' pub stores completed (vmcnt(0) drain) at this barrier
            __syncthreads();                    // B2
            if (tid == 0) {
                __hip_atomic_store(prog + b * FSTRIDE, t + 1,
                                   __ATOMIC_RELAXED, __HIP_MEMORY_SCOPE_AGENT);
                __asm__ __volatile__("" ::: "memory");
            }
            // neighbor-only spin: one thread per direction (R8-proven)
            if (tid == 0 && hasTop) {
                while (__hip_atomic_load(prog + (b - 1) * FSTRIDE,
                                         __ATOMIC_RELAXED, __HIP_MEMORY_SCOPE_AGENT) <= t)
                    __builtin_amdgcn_s_sleep(1);
                __asm__ __volatile__("" ::: "memory");
            }
            if (tid == 64 && hasBot) {
                while (__hip_atomic_load(prog + (b + 1) * FSTRIDE,
                                         __ATOMIC_RELAXED, __HIP_MEMORY_SCOPE_AGENT) <= t)
                    __builtin_amdgcn_s_sleep(1);
                __asm__ __volatile__("" ::: "memory");
            }
            __syncthreads();                    // spin done, flags observed
            // import halo rows (agent-scope loads read the L3-coherent copy)
            const fp16* pub = (t & 1) ? pub1 : pub0;
            if (tid < CPR) {
                if (hasTop)
                    *(half8*)&s_ub[0][tid * VEC] =
                        pub_load(&pub[((b - 1) * 2 + 1) * WC + tid * VEC]);
            } else {
                if (hasBot)
                    *(half8*)&s_ub[5][(tid - CPR) * VEC] =
                        pub_load(&pub[((b + 1) * 2 + 0) * WC + (tid - CPR) * VEC]);
            }
            __syncthreads();                    // B3: halo in place
        }
    }
}

extern "C" void kernel_launch(void* const* d_in, const int* in_sizes, int n_in,
                              void* d_out, int out_size, void* d_ws, size_t ws_size,
                              hipStream_t stream) {
    const float* t_dx = (const float*)d_in[0];
    const float* t_dy = (const float*)d_in[1];
    const float* t_dc = (const float*)d_in[2];
    const float* t_db = (const float*)d_in[3];
    const float* t_di = (const float*)d_in[4];
    float* out = (float*)d_out;

    fp16* pub0 = (fp16*)d_ws;                         // 256 blocks x 2 rows x 3072
    fp16* pub1 = pub0 + (size_t)NB * 2 * WC;          // double buffer (3 MB each)
    int*  prog = (int*)(pub1 + (size_t)NB * 2 * WC);  // padded flags, 32 KB

    // flags must be 0 at kernel start on every (replayed) call
    hipMemsetAsync(prog, 0, NB * FSTRIDE * sizeof(int), stream);

    void* args[] = { (void*)&t_dx, (void*)&t_dy, (void*)&t_dc, (void*)&t_db,
                     (void*)&t_di, (void*)&out, (void*)&pub0, (void*)&pub1,
                     (void*)&prog };
    hipLaunchCooperativeKernel((void*)tv_persist, dim3(NB), dim3(TPB),
                               args, 0, stream);
}

// Round 12
// 114.766 us; speedup vs baseline: 1.1589x; 1.1589x over previous
//
#include <hip/hip_runtime.h>

#define TAU 0.25f
#define SIGMA 0.5f

typedef _Float16 fp16;
typedef fp16 half8 __attribute__((ext_vector_type(8)));

constexpr int H = 1024, W = 1024, C = 3;
constexpr int WC  = W * C;         // 3072 elems per row
constexpr int VEC = 8;
constexpr int CPR = WC / VEC;      // 384 chunks per row
constexpr int TPB = 768;           // threads per block
constexpr int RB  = 4;             // rows per block
constexpr int NB  = H / RB;        // 256 blocks = 1 per CU
constexpr int ITS = 20;
constexpr int FSTRIDE = 32;        // flag padding: 128 B per block

__device__ __forceinline__ void ld8(const float* __restrict__ p, int i, float* v) {
    float4 a = *(const float4*)(p + i);
    float4 b = *(const float4*)(p + i + 4);
    v[0]=a.x; v[1]=a.y; v[2]=a.z; v[3]=a.w;
    v[4]=b.x; v[5]=b.y; v[6]=b.z; v[7]=b.w;
}

// packed clamp to [-w, w]  (v_pk_max_f16 / v_pk_min_f16)
__device__ __forceinline__ half8 clamp8(half8 v, half8 w) {
    return __builtin_elementwise_min(__builtin_elementwise_max(v, -w), w);
}

// agent-scope relaxed 16B store/load (coherent at L3; R8-proven)
__device__ __forceinline__ void pub_store(fp16* dst, half8 v) {
    union { half8 h; unsigned long long q[2]; } cv; cv.h = v;
    __hip_atomic_store((unsigned long long*)dst,     cv.q[0],
                       __ATOMIC_RELAXED, __HIP_MEMORY_SCOPE_AGENT);
    __hip_atomic_store((unsigned long long*)dst + 1, cv.q[1],
                       __ATOMIC_RELAXED, __HIP_MEMORY_SCOPE_AGENT);
}
__device__ __forceinline__ half8 pub_load(const fp16* src) {
    union { unsigned long long q[2]; half8 h; } cv;
    cv.q[0] = __hip_atomic_load((const unsigned long long*)src,
                                __ATOMIC_RELAXED, __HIP_MEMORY_SCOPE_AGENT);
    cv.q[1] = __hip_atomic_load((const unsigned long long*)src + 1,
                                __ATOMIC_RELAXED, __HIP_MEMORY_SCOPE_AGENT);
    return cv.h;
}

// Persistent kernel: 20 CP iterations, state in LDS; u in f32 registers.
// Arithmetic in packed fp16 (dual) / f32 (u update). Sync skeleton = R8/R11.
__global__ __launch_bounds__(TPB, 3) void tv_persist(
    const float* __restrict__ dx, const float* __restrict__ dy,
    const float* __restrict__ dc, const float* __restrict__ db,
    const float* __restrict__ di, float* __restrict__ out,
    fp16* __restrict__ pub0, fp16* __restrict__ pub1,
    int* __restrict__ prog)
{
    __shared__ fp16 s_ub[6][WC];   // rows y0-1 .. y0+4 (idx = r - y0 + 1)
    __shared__ fp16 s_px[4][WC];   // rows y0   .. y0+3
    __shared__ fp16 s_py[5][WC];   // idx0 = shadow row y0-1; idx r+1 = row y0+r
    // 92,160 B total

    const int b   = blockIdx.x;
    const int y0  = b * RB;
    const int tid = threadIdx.x;
    const bool hasTop = (b > 0), hasBot = (b < NB - 1);

    const int cx  = tid % CPR;
    const int rA  = tid / CPR;         // 0 or 1; thread owns rows rA and rA+2
    const int xc0 = cx * VEC;
    const bool lastCx = (cx == CPR - 1);

    // ---- init: LDS state + register invariants ----
    half8 wxr[2], wyr[2];
    float rcf[2][8], Af[2][8], Bf[2][8], uf[2][8];
    #pragma unroll
    for (int k = 0; k < 2; ++k) {
        int r  = rA + 2 * k;
        int gi = (y0 + r) * WC + xc0;
        float vv[8], cv[8], bv[8], xv[8], yv[8];
        ld8(di, gi, vv); ld8(dc, gi, cv); ld8(db, gi, bv);
        ld8(dx, gi, xv); ld8(dy, gi, yv);
        half8 hub, hz = {};
        #pragma unroll
        for (int j = 0; j < 8; ++j) {
            hub[j] = (fp16)vv[j];
            wxr[k][j] = (fp16)xv[j];
            wyr[k][j] = (fp16)yv[j];
            float rc = 1.0f / (1.0f + TAU * cv[j]);
            rcf[k][j] = rc;
            Af[k][j]  = TAU * rc;
            Bf[k][j]  = TAU * cv[j] * bv[j] * rc;
            uf[k][j]  = vv[j];
        }
        *(half8*)&s_ub[r + 1][xc0] = hub;
        *(half8*)&s_px[r][xc0]     = hz;
        *(half8*)&s_py[r + 1][xc0] = hz;
    }
    half8 wyS = {};
    if (tid < CPR) {
        if (hasTop) {                       // halo row y0-1: ub, shadow py, wy
            int x0 = tid * VEC;
            int gi = (y0 - 1) * WC + x0;
            float vv[8], yv[8];
            ld8(di, gi, vv); ld8(dy, gi, yv);
            half8 h, hz = {};
            #pragma unroll
            for (int j = 0; j < 8; ++j) { h[j] = (fp16)vv[j]; wyS[j] = (fp16)yv[j]; }
            *(half8*)&s_ub[0][x0] = h;
            *(half8*)&s_py[0][x0] = hz;
        }
    } else {
        if (hasBot) {                       // halo row y0+4: ub
            int x0 = (tid - CPR) * VEC;
            int gi = (y0 + 4) * WC + x0;
            float vv[8];
            ld8(di, gi, vv);
            half8 h;
            #pragma unroll
            for (int j = 0; j < 8; ++j) h[j] = (fp16)vv[j];
            *(half8*)&s_ub[5][x0] = h;
        }
    }
    __syncthreads();

    const fp16 hS = (fp16)0.5f;
    half8 pxn[2], pyn[2];
    for (int t = 0; t < ITS; ++t) {
        // ---------------- dual phase (packed fp16) ----------------
        #pragma unroll
        for (int k = 0; k < 2; ++k) {
            int r = rA + 2 * k;
            bool notBot = (y0 + r < H - 1);
            half8 ubC = *(half8*)&s_ub[r + 1][xc0];
            half8 ubN = lastCx ? ubC : *(half8*)&s_ub[r + 1][xc0 + 8];
            half8 ubD = *(half8*)&s_ub[r + 2][xc0];
            half8 pxo = *(half8*)&s_px[r][xc0];
            half8 pyo = *(half8*)&s_py[r + 1][xc0];

            half8 ubR = __builtin_shufflevector(ubC, ubN, 3,4,5,6,7,8,9,10);
            half8 gx = ubR - ubC;
            if (lastCx) { gx[5] = (fp16)0.f; gx[6] = (fp16)0.f; gx[7] = (fp16)0.f; }
            half8 gy;
            if (notBot) gy = ubD - ubC; else gy = half8{};

            half8 npx = clamp8(pxo + hS * gx, wxr[k]);
            half8 npy = clamp8(pyo + hS * gy, wyr[k]);

            *(half8*)&s_px[r][xc0]     = npx;   // only this thread read the old value
            *(half8*)&s_py[r + 1][xc0] = npy;
            pxn[k] = npx; pyn[k] = npy;
        }
        if (hasTop && tid < CPR) {              // shadow py row y0-1 (packed)
            int x0 = tid * VEC;
            half8 u0 = *(half8*)&s_ub[0][x0];
            half8 u1 = *(half8*)&s_ub[1][x0];
            half8 po = *(half8*)&s_py[0][x0];
            *(half8*)&s_py[0][x0] = clamp8(po + hS * (u1 - u0), wyS);
        }
        __syncthreads();                        // B1: px,py visible

        // ---------------- primal phase ----------------
        #pragma unroll
        for (int k = 0; k < 2; ++k) {
            int r = rA + 2 * k;
            bool notTop = (y0 + r > 0);
            half8 px8 = pxn[k], py8 = pyn[k];
            half8 pxP = (cx > 0) ? *(half8*)&s_px[r][xc0 - 8] : px8;
            half8 pxL = __builtin_shufflevector(pxP, px8, 5,6,7,8,9,10,11,12);
            half8 pyU = *(half8*)&s_py[r][xc0];   // r==0 -> shadow row
            half8 nub;
            float un8[8];
            #pragma unroll
            for (int j = 0; j < 8; ++j) {
                float d = (float)px8[j] + (float)py8[j];
                float l = (float)pxL[j];
                if (j < 3) l = (cx > 0) ? l : 0.0f;     // xc0+j >= C ?
                d -= l;
                d -= notTop ? (float)pyU[j] : 0.0f;
                float uo = uf[k][j];
                float un = fmaf(Af[k][j], d, fmaf(rcf[k][j], uo, Bf[k][j]));
                un8[j] = un;
                uf[k][j] = un;
                nub[j] = (fp16)(2.0f * un - uo);
            }
            *(half8*)&s_ub[r + 1][xc0] = nub;
            if (t == ITS - 1) {
                int gi = (y0 + r) * WC + xc0;
                *(float4*)(out + gi)     = make_float4(un8[0], un8[1], un8[2], un8[3]);
                *(float4*)(out + gi + 4) = make_float4(un8[4], un8[5], un8[6], un8[7]);
            } else {
                fp16* pub = (t & 1) ? pub1 : pub0;
                if (r == 0) pub_store(&pub[(b * 2 + 0) * WC + xc0], nub);  // top row
                if (r == 3) pub_store(&pub[(b * 2 + 1) * WC + xc0], nub);  // bottom row
            }
        }

        if (t < ITS - 1) {
            // all waves' pub stores completed (vmcnt(0) drain) at this barrier
            __syncthreads();                    // B2
            if (tid == 0) {
                __hip_atomic_store(prog + b * FSTRIDE, t + 1,
                                   __ATOMIC_RELAXED, __HIP_MEMORY_SCOPE_AGENT);
                __asm__ __volatile__("" ::: "memory");
            }
            // neighbor-only spin: one thread per direction (R8-proven)
            if (tid == 0 && hasTop) {
                while (__hip_atomic_load(prog + (b - 1) * FSTRIDE,
                                         __ATOMIC_RELAXED, __HIP_MEMORY_SCOPE_AGENT) <= t)
                    __builtin_amdgcn_s_sleep(1);
                __asm__ __volatile__("" ::: "memory");
            }
            if (tid == 64 && hasBot) {
                while (__hip_atomic_load(prog + (b + 1) * FSTRIDE,
                                         __ATOMIC_RELAXED, __HIP_MEMORY_SCOPE_AGENT) <= t)
                    __builtin_amdgcn_s_sleep(1);
                __asm__ __volatile__("" ::: "memory");
            }
            __syncthreads();                    // spin done, flags observed
            // import halo rows (agent-scope loads read the L3-coherent copy)
            const fp16* pub = (t & 1) ? pub1 : pub0;
            if (tid < CPR) {
                if (hasTop)
                    *(half8*)&s_ub[0][tid * VEC] =
                        pub_load(&pub[((b - 1) * 2 + 1) * WC + tid * VEC]);
            } else {
                if (hasBot)
                    *(half8*)&s_ub[5][(tid - CPR) * VEC] =
                        pub_load(&pub[((b + 1) * 2 + 0) * WC + (tid - CPR) * VEC]);
            }
            __syncthreads();                    // B3: halo in place
        }
    }
}

extern "C" void kernel_launch(void* const* d_in, const int* in_sizes, int n_in,
                              void* d_out, int out_size, void* d_ws, size_t ws_size,
                              hipStream_t stream) {
    const float* t_dx = (const float*)d_in[0];
    const float* t_dy = (const float*)d_in[1];
    const float* t_dc = (const float*)d_in[2];
    const float* t_db = (const float*)d_in[3];
    const float* t_di = (const float*)d_in[4];
    float* out = (float*)d_out;

    fp16* pub0 = (fp16*)d_ws;                         // 256 blocks x 2 rows x 3072
    fp16* pub1 = pub0 + (size_t)NB * 2 * WC;          // double buffer (3 MB each)
    int*  prog = (int*)(pub1 + (size_t)NB * 2 * WC);  // padded flags, 32 KB

    // flags must be 0 at kernel start on every (replayed) call
    hipMemsetAsync(prog, 0, NB * FSTRIDE * sizeof(int), stream);

    void* args[] = { (void*)&t_dx, (void*)&t_dy, (void*)&t_dc, (void*)&t_db,
                     (void*)&t_di, (void*)&out, (void*)&pub0, (void*)&pub1,
                     (void*)&prog };
    hipLaunchCooperativeKernel((void*)tv_persist, dim3(NB), dim3(TPB),
                               args, 0, stream);
}